// Round 1
// baseline (1298.714 us; speedup 1.0000x reference)
//
#include <hip/hip_runtime.h>
#include <hip/hip_bf16.h>

#define BN 8
#define CN 256
#define CQn 32
#define HN 128
#define WN 128
#define LST 132

using bf16 = __hip_bfloat16;

__device__ __forceinline__ float ldf(const float* p) { return *p; }
__device__ __forceinline__ float ldf(const bf16* p) { return __bfloat162float(*p); }
__device__ __forceinline__ void stf(float* p, float v) { *p = v; }
__device__ __forceinline__ void stf(bf16* p, float v) { *p = __float2bfloat16(v); }

// ---------------------------------------------------------------- proj q,k
__global__ __launch_bounds__(256) void proj_qk(
    const float* __restrict__ x, const float* __restrict__ Wq, const float* __restrict__ bq,
    const float* __restrict__ Wk, const float* __restrict__ bk,
    bf16* __restrict__ q, bf16* __restrict__ k) {
  __shared__ float xs[64][128];
  __shared__ float wqs[CQn][64];
  __shared__ float wks[CQn][64];
  __shared__ float bqs[CQn], bks[CQn];
  const int tid = threadIdx.x;
  const int b = blockIdx.x >> 7, h = blockIdx.x & 127;
  if (tid < CQn) { bqs[tid] = bq[tid]; bks[tid] = bk[tid]; }
  const int w0 = (tid & 63) * 2;
  const int g = tid >> 6;  // 0..3
  float accq[8][2] = {};
  float acck[8][2] = {};
  for (int cc = 0; cc < CN; cc += 64) {
    __syncthreads();
    for (int idx = tid; idx < 64 * 128; idx += 256) {
      int c = idx >> 7, ww = idx & 127;
      xs[c][ww] = x[(((size_t)b * CN + cc + c) * HN + h) * WN + ww];
    }
    for (int idx = tid; idx < CQn * 64; idx += 256) {
      int oc = idx >> 6, c = idx & 63;
      wqs[oc][c] = Wq[oc * CN + cc + c];
      wks[oc][c] = Wk[oc * CN + cc + c];
    }
    __syncthreads();
    for (int c4 = 0; c4 < 64; c4 += 4) {
      float xa[4][2];
#pragma unroll
      for (int a = 0; a < 4; ++a) {
        float2 v = *(const float2*)&xs[c4 + a][w0];
        xa[a][0] = v.x; xa[a][1] = v.y;
      }
#pragma unroll
      for (int r = 0; r < 8; ++r) {
        const int oc = g * 8 + r;
        float4 wq4 = *(const float4*)&wqs[oc][c4];
        float4 wk4 = *(const float4*)&wks[oc][c4];
        float wqa[4] = {wq4.x, wq4.y, wq4.z, wq4.w};
        float wka[4] = {wk4.x, wk4.y, wk4.z, wk4.w};
#pragma unroll
        for (int a = 0; a < 4; ++a) {
          accq[r][0] += wqa[a] * xa[a][0];
          accq[r][1] += wqa[a] * xa[a][1];
          acck[r][0] += wka[a] * xa[a][0];
          acck[r][1] += wka[a] * xa[a][1];
        }
      }
    }
  }
#pragma unroll
  for (int r = 0; r < 8; ++r) {
    int oc = g * 8 + r;
    size_t off = (((size_t)b * CQn + oc) * HN + h) * WN + w0;
    q[off]     = __float2bfloat16(accq[r][0] + bqs[oc]);
    q[off + 1] = __float2bfloat16(accq[r][1] + bqs[oc]);
    k[off]     = __float2bfloat16(acck[r][0] + bks[oc]);
    k[off + 1] = __float2bfloat16(acck[r][1] + bks[oc]);
  }
}

// ------------------------------------------------- transpose [p][r][c] -> [p][c][r], out bf16
template <typename TIn>
__global__ __launch_bounds__(256) void transpose_bf16(const TIn* __restrict__ in,
                                                      bf16* __restrict__ out) {
  __shared__ float tile[32][33];
  const int blk = blockIdx.x;
  const int p = blk >> 4, t = blk & 15;
  const int r0 = (t >> 2) * 32, c0 = (t & 3) * 32;
  const int tx = threadIdx.x & 31, ty = threadIdx.x >> 5;  // ty 0..7
  const TIn* ip = in + (size_t)p * 128 * 128;
#pragma unroll
  for (int rr = 0; rr < 4; ++rr)
    tile[ty + 8 * rr][tx] = ldf(&ip[(r0 + ty + 8 * rr) * 128 + c0 + tx]);
  __syncthreads();
  bf16* op = out + (size_t)p * 128 * 128;
#pragma unroll
  for (int rr = 0; rr < 4; ++rr)
    op[(c0 + ty + 8 * rr) * 128 + r0 + tx] = __float2bfloat16(tile[tx][ty + 8 * rr]);
}

// ------------------------------------------------- out[p][h][w] += tT[p][w][h]
__global__ __launch_bounds__(256) void transpose_add(const bf16* __restrict__ tT,
                                                     float* __restrict__ out) {
  __shared__ float tile[32][33];
  const int blk = blockIdx.x;
  const int p = blk >> 4, t = blk & 15;
  const int h0 = (t >> 2) * 32, w0 = (t & 3) * 32;
  const int tx = threadIdx.x & 31, ty = threadIdx.x >> 5;
  const bf16* ip = tT + (size_t)p * 128 * 128;
#pragma unroll
  for (int rr = 0; rr < 4; ++rr)
    tile[ty + 8 * rr][tx] = __bfloat162float(ip[(w0 + ty + 8 * rr) * 128 + h0 + tx]);
  __syncthreads();
  float* op = out + (size_t)p * 128 * 128;
#pragma unroll
  for (int rr = 0; rr < 4; ++rr)
    op[(h0 + ty + 8 * rr) * 128 + w0 + tx] += tile[tx][ty + 8 * rr];
}

// ------------------------------------------------- 1D attention along last axis
// slices (b, r); q/k layout [B][CQ][128][128]; xsrc/outp layout [B][CN][128][128]
// dynamic LDS: qs 4096 | ks 4096 | Ls 128*LST | xsv 32*LST | red 256 | rsum 128
template <typename XT, typename OT, bool ADD_EYE>
__global__ __launch_bounds__(256) void attn_1d(
    const bf16* __restrict__ qsrc, const bf16* __restrict__ ksrc,
    const XT* __restrict__ xsrc, OT* __restrict__ outp) {
  extern __shared__ float sm[];
  float* qs  = sm;                  // 32*128
  float* ks  = sm + 4096;           // 32*128
  float* Ls  = sm + 8192;           // 128*LST
  float* xsv = sm + 8192 + 128 * LST;          // 32*LST
  float* red = sm + 8192 + 160 * LST;          // 256
  float* rsum = sm + 8192 + 160 * LST + 256;   // 128
  const int tid = threadIdx.x;
  const int b = blockIdx.x >> 7, r = blockIdx.x & 127;

  for (int idx = tid; idx < CQn * 128; idx += 256) {
    int c = idx >> 7, j = idx & 127;
    size_t off = (((size_t)b * CQn + c) * 128 + r) * 128 + j;
    qs[idx] = __bfloat162float(qsrc[off]);
    ks[idx] = __bfloat162float(ksrc[off]);
  }
  __syncthreads();

  // logits L[i][j] = sum_c qs[c][i]*ks[c][j] (+ eye)
#pragma unroll
  for (int g = 0; g < 4; ++g) {
    int t = tid + g * 256;
    int i0 = (t >> 5) * 4, j0 = (t & 31) * 4;
    float acc[4][4] = {};
    for (int c = 0; c < CQn; ++c) {
      float4 qv = *(const float4*)&qs[c * 128 + i0];
      float4 kv = *(const float4*)&ks[c * 128 + j0];
      float qa[4] = {qv.x, qv.y, qv.z, qv.w};
      float ka[4] = {kv.x, kv.y, kv.z, kv.w};
#pragma unroll
      for (int ii = 0; ii < 4; ++ii)
#pragma unroll
        for (int jj = 0; jj < 4; ++jj) acc[ii][jj] += qa[ii] * ka[jj];
    }
#pragma unroll
    for (int ii = 0; ii < 4; ++ii) {
      if (ADD_EYE) {
        int i = i0 + ii;
        if (i >= j0 && i < j0 + 4) acc[ii][i - j0] += 1.0f;
      }
      float4 o = make_float4(acc[ii][0], acc[ii][1], acc[ii][2], acc[ii][3]);
      *(float4*)&Ls[(i0 + ii) * LST + j0] = o;
    }
  }
  __syncthreads();

  // softmax: exp(L - rowmax) in place + row sums
  {
    const int row = tid & 127, jb = (tid >> 7) * 64;
    float m = -1e30f;
    for (int j = 0; j < 64; ++j) m = fmaxf(m, Ls[row * LST + jb + j]);
    red[tid] = m;
    __syncthreads();
    m = fmaxf(red[row], red[row + 128]);
    float s = 0.f;
    for (int j = 0; j < 64; ++j) {
      float e = __expf(Ls[row * LST + jb + j] - m);
      Ls[row * LST + jb + j] = e;
      s += e;
    }
    __syncthreads();
    red[tid] = s;
    __syncthreads();
    if (tid < 128) rsum[tid] = red[tid] + red[tid + 128];
  }
  const int ci0 = (tid >> 5) * 4;  // 0..28
  const int il = tid & 31;
  float rinv[4];
  __syncthreads();
#pragma unroll
  for (int a = 0; a < 4; ++a) rinv[a] = 1.0f / rsum[il + 32 * a];

  // PV: t[cc][i] = sum_j P[i][j] * xs[cc][j] / rsum[i]
  for (int cc0 = 0; cc0 < CN; cc0 += 32) {
    __syncthreads();
    for (int idx = tid; idx < 32 * 128; idx += 256) {
      int c = idx >> 7, j = idx & 127;
      xsv[c * LST + j] = ldf(&xsrc[(((size_t)b * CN + cc0 + c) * 128 + r) * 128 + j]);
    }
    __syncthreads();
    float acc[4][4] = {};  // [ci][a]
    for (int j0 = 0; j0 < 128; j0 += 4) {
      float xa[4][4], pa[4][4];
#pragma unroll
      for (int ci = 0; ci < 4; ++ci) {
        float4 v = *(const float4*)&xsv[(ci0 + ci) * LST + j0];
        xa[ci][0] = v.x; xa[ci][1] = v.y; xa[ci][2] = v.z; xa[ci][3] = v.w;
      }
#pragma unroll
      for (int a = 0; a < 4; ++a) {
        float4 v = *(const float4*)&Ls[(il + 32 * a) * LST + j0];
        pa[a][0] = v.x; pa[a][1] = v.y; pa[a][2] = v.z; pa[a][3] = v.w;
      }
#pragma unroll
      for (int ci = 0; ci < 4; ++ci)
#pragma unroll
        for (int a = 0; a < 4; ++a)
          acc[ci][a] += xa[ci][0] * pa[a][0] + xa[ci][1] * pa[a][1] +
                        xa[ci][2] * pa[a][2] + xa[ci][3] * pa[a][3];
    }
#pragma unroll
    for (int ci = 0; ci < 4; ++ci) {
      size_t base = (((size_t)b * CN + cc0 + ci0 + ci) * 128 + r) * 128 + il;
#pragma unroll
      for (int a = 0; a < 4; ++a) stf(&outp[base + 32 * a], acc[ci][a] * rinv[a]);
    }
  }
}

// ------------------------------------------------- out = gamma*(Wv @ t + 2bv) + x, in place
// dynamic LDS: ts 256*64 | wvs 64*260
__global__ __launch_bounds__(256) void final_wv(
    float* __restrict__ out, const float* __restrict__ x,
    const float* __restrict__ Wv, const float* __restrict__ bv,
    const float* __restrict__ gamma) {
  extern __shared__ float sm[];
  float* ts = sm;            // [256][64]
  float* wvs = sm + 16384;   // [64][260]
  const int tid = threadIdx.x;
  const int wseg = blockIdx.x & 1;
  const int bh = blockIdx.x >> 1;
  const int b = bh >> 7, h = bh & 127;
  const int w0 = wseg * 64;
  const float g = gamma[0];
  for (int idx = tid; idx < CN * 64; idx += 256) {
    int c = idx >> 6, p = idx & 63;
    ts[c * 64 + p] = out[(((size_t)b * CN + c) * HN + h) * WN + w0 + p];
  }
  const int p0 = (tid & 15) * 4;
  const int cog = tid >> 4;  // 0..15
  for (int coc = 0; coc < CN; coc += 64) {
    __syncthreads();
    for (int idx = tid; idx < 64 * CN; idx += 256) {
      int co = idx >> 8, c = idx & 255;
      wvs[co * 260 + c] = Wv[(size_t)(coc + co) * CN + c];
    }
    __syncthreads();
    float acc[4][4] = {};  // [rr][p]
    for (int c0 = 0; c0 < CN; c0 += 4) {
      float ta[4][4];
#pragma unroll
      for (int a = 0; a < 4; ++a) {
        float4 v = *(const float4*)&ts[(c0 + a) * 64 + p0];
        ta[a][0] = v.x; ta[a][1] = v.y; ta[a][2] = v.z; ta[a][3] = v.w;
      }
#pragma unroll
      for (int rr = 0; rr < 4; ++rr) {
        float4 wv4 = *(const float4*)&wvs[(cog + 16 * rr) * 260 + c0];
        float wa[4] = {wv4.x, wv4.y, wv4.z, wv4.w};
#pragma unroll
        for (int p = 0; p < 4; ++p)
          acc[rr][p] += wa[0] * ta[0][p] + wa[1] * ta[1][p] + wa[2] * ta[2][p] + wa[3] * ta[3][p];
      }
    }
#pragma unroll
    for (int rr = 0; rr < 4; ++rr) {
      int co = coc + cog + 16 * rr;
      size_t base = (((size_t)b * CN + co) * HN + h) * WN + w0 + p0;
      float4 xv = *(const float4*)&x[base];
      float bb = 2.0f * bv[co];
      float4 ov;
      ov.x = g * (acc[rr][0] + bb) + xv.x;
      ov.y = g * (acc[rr][1] + bb) + xv.y;
      ov.z = g * (acc[rr][2] + bb) + xv.z;
      ov.w = g * (acc[rr][3] + bb) + xv.w;
      *(float4*)&out[base] = ov;
    }
  }
}

extern "C" void kernel_launch(void* const* d_in, const int* in_sizes, int n_in,
                              void* d_out, int out_size, void* d_ws, size_t ws_size,
                              hipStream_t stream) {
  const float* x     = (const float*)d_in[0];
  const float* Wq    = (const float*)d_in[1];
  const float* bq    = (const float*)d_in[2];
  const float* Wk    = (const float*)d_in[3];
  const float* bk    = (const float*)d_in[4];
  const float* Wv    = (const float*)d_in[5];
  const float* bv    = (const float*)d_in[6];
  const float* gamma = (const float*)d_in[7];
  float* out = (float*)d_out;

  const size_t QSZ = (size_t)BN * CQn * HN * WN;  // 4,194,304
  const size_t XSZ = (size_t)BN * CN * HN * WN;   // 33,554,432
  bf16* wsb = (bf16*)d_ws;
  bf16* q  = wsb;
  bf16* k  = wsb + QSZ;
  bf16* qT = wsb + 2 * QSZ;
  bf16* kT = wsb + 3 * QSZ;
  bf16* xT = wsb + 4 * QSZ;
  if (ws_size < (4 * QSZ + XSZ) * sizeof(bf16)) {
    // visible sentinel: workspace too small
    hipMemsetAsync(d_out, 0x7f, (size_t)out_size * sizeof(float), stream);
    return;
  }

  const int ATTN_LDS = (8192 + 160 * LST + 384) * 4;   // 118,784 B
  const int FINAL_LDS = (16384 + 64 * 260) * 4;        // 132,096 B
  auto* fa_row = attn_1d<float, float, false>;
  auto* fa_col = attn_1d<bf16, bf16, true>;
  hipFuncSetAttribute((const void*)fa_row, hipFuncAttributeMaxDynamicSharedMemorySize, ATTN_LDS);
  hipFuncSetAttribute((const void*)fa_col, hipFuncAttributeMaxDynamicSharedMemorySize, ATTN_LDS);
  hipFuncSetAttribute((const void*)final_wv, hipFuncAttributeMaxDynamicSharedMemorySize, FINAL_LDS);

  proj_qk<<<BN * HN, 256, 0, stream>>>(x, Wq, bq, Wk, bk, q, k);
  transpose_bf16<bf16><<<2 * BN * CQn * 16, 256, 0, stream>>>(q, qT);
  transpose_bf16<float><<<BN * CN * 16, 256, 0, stream>>>(x, xT);
  // row attention -> t_w in d_out
  fa_row<<<BN * HN, 256, ATTN_LDS, stream>>>(q, k, x, out);
  // column attention (on transposed tensors), in place on xT
  fa_col<<<BN * WN, 256, ATTN_LDS, stream>>>(qT, kT, xT, xT);
  // d_out += t_h (transposed back)
  transpose_add<<<BN * CN * 16, 256, 0, stream>>>(xT, out);
  // out = gamma*(Wv@t + 2bv) + x
  final_wv<<<BN * HN * (WN / 64), 256, FINAL_LDS, stream>>>(out, x, Wv, bv, gamma);
}

// Round 2
// 754.948 us; speedup vs baseline: 1.7203x; 1.7203x over previous
//
#include <hip/hip_runtime.h>
#include <hip/hip_bf16.h>

#define BN 8
#define CN 256
#define CQn 32
#define HN 128
#define WN 128
#define LST 132

using bf16 = __hip_bfloat16;
typedef short short8 __attribute__((ext_vector_type(8)));
typedef float f32x4 __attribute__((ext_vector_type(4)));

__device__ __forceinline__ float ldf(const float* p) { return *p; }
__device__ __forceinline__ float ldf(const bf16* p) { return __bfloat162float(*p); }
__device__ __forceinline__ void stf(float* p, float v) { *p = v; }
__device__ __forceinline__ void stf(bf16* p, float v) { *p = __float2bfloat16(v); }
__device__ __forceinline__ unsigned short f2bu(float v) {
  bf16 h = __float2bfloat16(v);
  return *(unsigned short*)&h;
}
__device__ __forceinline__ float bu2f(unsigned short u) {
  return __bfloat162float(*(const bf16*)&u);
}

// ---------------------------------------------------------------- proj q,k
__global__ __launch_bounds__(256) void proj_qk(
    const float* __restrict__ x, const float* __restrict__ Wq, const float* __restrict__ bq,
    const float* __restrict__ Wk, const float* __restrict__ bk,
    bf16* __restrict__ q, bf16* __restrict__ k) {
  __shared__ float xs[64][128];
  __shared__ float wqs[CQn][64];
  __shared__ float wks[CQn][64];
  __shared__ float bqs[CQn], bks[CQn];
  const int tid = threadIdx.x;
  const int b = blockIdx.x >> 7, h = blockIdx.x & 127;
  if (tid < CQn) { bqs[tid] = bq[tid]; bks[tid] = bk[tid]; }
  const int w0 = (tid & 63) * 2;
  const int g = tid >> 6;  // 0..3
  float accq[8][2] = {};
  float acck[8][2] = {};
  for (int cc = 0; cc < CN; cc += 64) {
    __syncthreads();
    for (int idx = tid; idx < 64 * 128; idx += 256) {
      int c = idx >> 7, ww = idx & 127;
      xs[c][ww] = x[(((size_t)b * CN + cc + c) * HN + h) * WN + ww];
    }
    for (int idx = tid; idx < CQn * 64; idx += 256) {
      int oc = idx >> 6, c = idx & 63;
      wqs[oc][c] = Wq[oc * CN + cc + c];
      wks[oc][c] = Wk[oc * CN + cc + c];
    }
    __syncthreads();
    for (int c4 = 0; c4 < 64; c4 += 4) {
      float xa[4][2];
#pragma unroll
      for (int a = 0; a < 4; ++a) {
        float2 v = *(const float2*)&xs[c4 + a][w0];
        xa[a][0] = v.x; xa[a][1] = v.y;
      }
#pragma unroll
      for (int r = 0; r < 8; ++r) {
        const int oc = g * 8 + r;
        float4 wq4 = *(const float4*)&wqs[oc][c4];
        float4 wk4 = *(const float4*)&wks[oc][c4];
        float wqa[4] = {wq4.x, wq4.y, wq4.z, wq4.w};
        float wka[4] = {wk4.x, wk4.y, wk4.z, wk4.w};
#pragma unroll
        for (int a = 0; a < 4; ++a) {
          accq[r][0] += wqa[a] * xa[a][0];
          accq[r][1] += wqa[a] * xa[a][1];
          acck[r][0] += wka[a] * xa[a][0];
          acck[r][1] += wka[a] * xa[a][1];
        }
      }
    }
  }
#pragma unroll
  for (int r = 0; r < 8; ++r) {
    int oc = g * 8 + r;
    size_t off = (((size_t)b * CQn + oc) * HN + h) * WN + w0;
    q[off]     = __float2bfloat16(accq[r][0] + bqs[oc]);
    q[off + 1] = __float2bfloat16(accq[r][1] + bqs[oc]);
    k[off]     = __float2bfloat16(acck[r][0] + bks[oc]);
    k[off + 1] = __float2bfloat16(acck[r][1] + bks[oc]);
  }
}

// ------------------------------------------------- transpose [p][r][c] -> [p][c][r], out bf16
template <typename TIn>
__global__ __launch_bounds__(256) void transpose_bf16(const TIn* __restrict__ in,
                                                      bf16* __restrict__ out) {
  __shared__ float tile[32][33];
  const int blk = blockIdx.x;
  const int p = blk >> 4, t = blk & 15;
  const int r0 = (t >> 2) * 32, c0 = (t & 3) * 32;
  const int tx = threadIdx.x & 31, ty = threadIdx.x >> 5;  // ty 0..7
  const TIn* ip = in + (size_t)p * 128 * 128;
#pragma unroll
  for (int rr = 0; rr < 4; ++rr)
    tile[ty + 8 * rr][tx] = ldf(&ip[(r0 + ty + 8 * rr) * 128 + c0 + tx]);
  __syncthreads();
  bf16* op = out + (size_t)p * 128 * 128;
#pragma unroll
  for (int rr = 0; rr < 4; ++rr)
    op[(c0 + ty + 8 * rr) * 128 + r0 + tx] = __float2bfloat16(tile[tx][ty + 8 * rr]);
}

// ------------------------------------------------- OLD fallback: out[p][h][w] += tT[p][w][h]
__global__ __launch_bounds__(256) void transpose_add(const bf16* __restrict__ tT,
                                                     float* __restrict__ out) {
  __shared__ float tile[32][33];
  const int blk = blockIdx.x;
  const int p = blk >> 4, t = blk & 15;
  const int h0 = (t >> 2) * 32, w0 = (t & 3) * 32;
  const int tx = threadIdx.x & 31, ty = threadIdx.x >> 5;
  const bf16* ip = tT + (size_t)p * 128 * 128;
#pragma unroll
  for (int rr = 0; rr < 4; ++rr)
    tile[ty + 8 * rr][tx] = __bfloat162float(ip[(w0 + ty + 8 * rr) * 128 + h0 + tx]);
  __syncthreads();
  float* op = out + (size_t)p * 128 * 128;
#pragma unroll
  for (int rr = 0; rr < 4; ++rr)
    op[(h0 + ty + 8 * rr) * 128 + w0 + tx] += tile[tx][ty + 8 * rr];
}

// ------------------------------------------------- Wv fp32 -> bf16
__global__ __launch_bounds__(256) void wv_to_bf16(const float* __restrict__ Wv,
                                                  bf16* __restrict__ Wvb) {
  int i = blockIdx.x * 256 + threadIdx.x;
  Wvb[i] = __float2bfloat16(Wv[i]);
}

// ------------------------------------------------- 1D attention along last axis
// slices (b, r); q/k layout [B][CQ][128][128]; xsrc layout [B][CN][128][128]
// PACKED=false: outp[b][c][r][j] (OT). PACKED=true: outp = twP bf16 c8-packed:
//   elem E(b,c,h,w) = (((b*32+(c>>3))*128+h)*128+w)*8 + (c&7)
template <typename XT, typename OT, bool ADD_EYE, bool PACKED>
__global__ __launch_bounds__(256) void attn_1d(
    const bf16* __restrict__ qsrc, const bf16* __restrict__ ksrc,
    const XT* __restrict__ xsrc, OT* __restrict__ outp) {
  extern __shared__ float sm[];
  float* qs  = sm;                  // 32*128
  float* ks  = sm + 4096;           // 32*128
  float* Ls  = sm + 8192;           // 128*LST
  float* xsv = sm + 8192 + 128 * LST;          // 32*LST
  float* red = sm + 8192 + 160 * LST;          // 256
  float* rsum = sm + 8192 + 160 * LST + 256;   // 128
  const int tid = threadIdx.x;
  const int b = blockIdx.x >> 7, r = blockIdx.x & 127;

  for (int idx = tid; idx < CQn * 128; idx += 256) {
    int c = idx >> 7, j = idx & 127;
    size_t off = (((size_t)b * CQn + c) * 128 + r) * 128 + j;
    qs[idx] = __bfloat162float(qsrc[off]);
    ks[idx] = __bfloat162float(ksrc[off]);
  }
  __syncthreads();

  // logits L[i][j] = sum_c qs[c][i]*ks[c][j] (+ eye)
#pragma unroll
  for (int g = 0; g < 4; ++g) {
    int t = tid + g * 256;
    int i0 = (t >> 5) * 4, j0 = (t & 31) * 4;
    float acc[4][4] = {};
    for (int c = 0; c < CQn; ++c) {
      float4 qv = *(const float4*)&qs[c * 128 + i0];
      float4 kv = *(const float4*)&ks[c * 128 + j0];
      float qa[4] = {qv.x, qv.y, qv.z, qv.w};
      float ka[4] = {kv.x, kv.y, kv.z, kv.w};
#pragma unroll
      for (int ii = 0; ii < 4; ++ii)
#pragma unroll
        for (int jj = 0; jj < 4; ++jj) acc[ii][jj] += qa[ii] * ka[jj];
    }
#pragma unroll
    for (int ii = 0; ii < 4; ++ii) {
      if (ADD_EYE) {
        int i = i0 + ii;
        if (i >= j0 && i < j0 + 4) acc[ii][i - j0] += 1.0f;
      }
      float4 o = make_float4(acc[ii][0], acc[ii][1], acc[ii][2], acc[ii][3]);
      *(float4*)&Ls[(i0 + ii) * LST + j0] = o;
    }
  }
  __syncthreads();

  // softmax: exp(L - rowmax) in place + row sums
  {
    const int row = tid & 127, jb = (tid >> 7) * 64;
    float m = -1e30f;
    for (int j = 0; j < 64; ++j) m = fmaxf(m, Ls[row * LST + jb + j]);
    red[tid] = m;
    __syncthreads();
    m = fmaxf(red[row], red[row + 128]);
    float s = 0.f;
    for (int j = 0; j < 64; ++j) {
      float e = __expf(Ls[row * LST + jb + j] - m);
      Ls[row * LST + jb + j] = e;
      s += e;
    }
    __syncthreads();
    red[tid] = s;
    __syncthreads();
    if (tid < 128) rsum[tid] = red[tid] + red[tid + 128];
  }
  const int ci0 = (tid >> 5) * 4;  // 0..28
  const int il = tid & 31;
  float rinv[4];
  __syncthreads();
#pragma unroll
  for (int a = 0; a < 4; ++a) rinv[a] = 1.0f / rsum[il + 32 * a];

  // PV: t[cc][i] = sum_j P[i][j] * xs[cc][j] / rsum[i]
  for (int cc0 = 0; cc0 < CN; cc0 += 32) {
    __syncthreads();
    for (int idx = tid; idx < 32 * 128; idx += 256) {
      int c = idx >> 7, j = idx & 127;
      xsv[c * LST + j] = ldf(&xsrc[(((size_t)b * CN + cc0 + c) * 128 + r) * 128 + j]);
    }
    __syncthreads();
    float acc[4][4] = {};  // [ci][a]
    for (int j0 = 0; j0 < 128; j0 += 4) {
      float xa[4][4], pa[4][4];
#pragma unroll
      for (int ci = 0; ci < 4; ++ci) {
        float4 v = *(const float4*)&xsv[(ci0 + ci) * LST + j0];
        xa[ci][0] = v.x; xa[ci][1] = v.y; xa[ci][2] = v.z; xa[ci][3] = v.w;
      }
#pragma unroll
      for (int a = 0; a < 4; ++a) {
        float4 v = *(const float4*)&Ls[(il + 32 * a) * LST + j0];
        pa[a][0] = v.x; pa[a][1] = v.y; pa[a][2] = v.z; pa[a][3] = v.w;
      }
#pragma unroll
      for (int ci = 0; ci < 4; ++ci)
#pragma unroll
        for (int a = 0; a < 4; ++a)
          acc[ci][a] += xa[ci][0] * pa[a][0] + xa[ci][1] * pa[a][1] +
                        xa[ci][2] * pa[a][2] + xa[ci][3] * pa[a][3];
    }
    if constexpr (PACKED) {
      // bounce normalized bf16 through xsv, then coalesced 16B chunk stores
      __syncthreads();
      unsigned short* xu = (unsigned short*)xsv;
#pragma unroll
      for (int ci = 0; ci < 4; ++ci)
#pragma unroll
        for (int a = 0; a < 4; ++a)
          xu[(ci0 + ci) * 132 + il + 32 * a] = f2bu(acc[ci][a] * rinv[a]);
      __syncthreads();
      unsigned short* ou = (unsigned short*)outp;
#pragma unroll
      for (int p = 0; p < 2; ++p) {
        int idx = p * 256 + tid;        // 0..511: 4 c-chunks x 128 px
        int cgL = idx >> 7, px = idx & 127;
        unsigned short tmp[8];
#pragma unroll
        for (int e = 0; e < 8; ++e) tmp[e] = xu[(cgL * 8 + e) * 132 + px];
        size_t g16 = (((size_t)b * 32 + (cc0 >> 3) + cgL) * 128 + r) * 128 + px;
        *(uint4*)&ou[g16 * 8] = *(const uint4*)tmp;
      }
    } else {
#pragma unroll
      for (int ci = 0; ci < 4; ++ci) {
        size_t base = (((size_t)b * CN + cc0 + ci0 + ci) * 128 + r) * 128 + il;
#pragma unroll
        for (int a = 0; a < 4; ++a) stf(&outp[base + 32 * a], acc[ci][a] * rinv[a]);
      }
    }
  }
}

// ------------------------------------------------- twP[b][cg][h][w][8] += t_hT[b][c][w][h]
__global__ __launch_bounds__(256) void packed_merge(const bf16* __restrict__ thT,
                                                    bf16* __restrict__ twP) {
  __shared__ unsigned short ths[8 * 32 * 36];  // [e][ww][hh] stride 36 (8B aligned, 2-way banks)
  const int tid = threadIdx.x;
  const int blk = blockIdx.x;
  const int tI = blk & 15;
  const int cgI = (blk >> 4) & 31;
  const int b = blk >> 9;
  const int w0 = (tI >> 2) * 32, h0 = (tI & 3) * 32;
  {
    const int e = tid >> 5, ww = tid & 31;
    const unsigned short* src = (const unsigned short*)(thT +
        ((((size_t)b * 256 + cgI * 8 + e) * 128) + (w0 + ww)) * 128 + h0);
    unsigned short* dst = &ths[(e * 32 + ww) * 36];
#pragma unroll
    for (int j = 0; j < 8; ++j)
      *(uint2*)&dst[j * 4] = *(const uint2*)&src[j * 4];
  }
  __syncthreads();
  unsigned short* twu = (unsigned short*)twP;
#pragma unroll
  for (int rep = 0; rep < 4; ++rep) {
    int cell = rep * 256 + tid;
    int hh = cell >> 5, ww = cell & 31;  // lanes vary ww -> coalesced 16B
    size_t g16 = ((((size_t)b * 32 + cgI) * 128) + h0 + hh) * 128 + (w0 + ww);
    uint4 cur = *(const uint4*)&twu[g16 * 8];
    unsigned short cu[8];
    *(uint4*)cu = cur;
#pragma unroll
    for (int e = 0; e < 8; ++e)
      cu[e] = f2bu(bu2f(cu[e]) + bu2f(ths[(e * 32 + ww) * 36 + hh]));
    *(uint4*)&twu[g16 * 8] = *(const uint4*)cu;
  }
}

// ------------------------------------------------- MFMA final GEMM
// out[b][co][h][w] = gamma*(sum_c Wv[co][c]*t[c] + 2bv[co]) + x ;  t from twP (c8-packed bf16)
// BM=256(co) x BN=128(w, one h-row) x K=256, BK=64; 8 waves (4m x 2n), wave tile 64x64.
__global__ __launch_bounds__(512) void final_mfma(
    const bf16* __restrict__ twP, const bf16* __restrict__ Wvb,
    const float* __restrict__ x, const float* __restrict__ bv,
    const float* __restrict__ gamma, float* __restrict__ out) {
  __shared__ short As[256][64];  // [co][c-in-tile], chunk-swizzled: slot = cg ^ (co&7)
  __shared__ short Bs[128][64];  // [w][c-in-tile],  chunk-swizzled: slot = cg ^ (w&7)
  const int tid = threadIdx.x;
  const int b = blockIdx.x >> 7, h = blockIdx.x & 127;
  const int lane = tid & 63;
  const int wid = tid >> 6;
  const int wm = wid >> 1, wn = wid & 1;
  const int l15 = lane & 15, lg = lane >> 4;
  const unsigned short* twu = (const unsigned short*)twP;

  f32x4 acc[4][4];
#pragma unroll
  for (int m = 0; m < 4; ++m)
#pragma unroll
    for (int n = 0; n < 4; ++n)
#pragma unroll
      for (int e = 0; e < 4; ++e) acc[m][n][e] = 0.f;

  for (int k0 = 0; k0 < 256; k0 += 64) {
    __syncthreads();
    // stage As: 2048 chunks (256 co x 8 cg)
#pragma unroll
    for (int p = 0; p < 4; ++p) {
      int idx = p * 512 + tid;
      int co = idx >> 3, cg = idx & 7;
      uint4 v = *(const uint4*)&Wvb[(size_t)co * 256 + k0 + cg * 8];
      *(uint4*)&As[co][(cg ^ (co & 7)) * 8] = v;
    }
    // stage Bs: 1024 chunks (128 w x 8 cg)
#pragma unroll
    for (int p = 0; p < 2; ++p) {
      int idx = p * 512 + tid;
      int w = idx & 127, cgL = idx >> 7;
      size_t g16 = (((size_t)b * 32 + (k0 >> 3) + cgL) * 128 + h) * 128 + w;
      uint4 v = *(const uint4*)&twu[g16 * 8];
      *(uint4*)&Bs[w][(cgL ^ (w & 7)) * 8] = v;
    }
    __syncthreads();
    short8 a[4][2], bb[4][2];
#pragma unroll
    for (int m = 0; m < 4; ++m)
#pragma unroll
      for (int kk = 0; kk < 2; ++kk) {
        int co = wm * 64 + m * 16 + l15;
        int cg = kk * 4 + lg;
        a[m][kk] = *(const short8*)&As[co][(cg ^ (co & 7)) * 8];
      }
#pragma unroll
    for (int n = 0; n < 4; ++n)
#pragma unroll
      for (int kk = 0; kk < 2; ++kk) {
        int w = wn * 64 + n * 16 + l15;
        int cg = kk * 4 + lg;
        bb[n][kk] = *(const short8*)&Bs[w][(cg ^ (w & 7)) * 8];
      }
#pragma unroll
    for (int kk = 0; kk < 2; ++kk)
#pragma unroll
      for (int m = 0; m < 4; ++m)
#pragma unroll
        for (int n = 0; n < 4; ++n)
          acc[m][n] = __builtin_amdgcn_mfma_f32_16x16x32_bf16(a[m][kk], bb[n][kk], acc[m][n], 0, 0, 0);
  }

  const float g = gamma[0];
  float bvv[4][4];
#pragma unroll
  for (int m = 0; m < 4; ++m)
#pragma unroll
    for (int rr = 0; rr < 4; ++rr)
      bvv[m][rr] = 2.0f * bv[wm * 64 + m * 16 + lg * 4 + rr];
#pragma unroll
  for (int m = 0; m < 4; ++m) {
#pragma unroll
    for (int n = 0; n < 4; ++n) {
      int w = wn * 64 + n * 16 + l15;
#pragma unroll
      for (int rr = 0; rr < 4; ++rr) {
        int co = wm * 64 + m * 16 + lg * 4 + rr;
        size_t o = (((size_t)b * 256 + co) * 128 + h) * 128 + w;
        out[o] = g * (acc[m][n][rr] + bvv[m][rr]) + x[o];
      }
    }
  }
}

// ------------------------------------------------- OLD fallback final (VALU fp32)
__global__ __launch_bounds__(256) void final_wv(
    float* __restrict__ out, const float* __restrict__ x,
    const float* __restrict__ Wv, const float* __restrict__ bv,
    const float* __restrict__ gamma) {
  extern __shared__ float sm[];
  float* ts = sm;            // [256][64]
  float* wvs = sm + 16384;   // [64][260]
  const int tid = threadIdx.x;
  const int wseg = blockIdx.x & 1;
  const int bh = blockIdx.x >> 1;
  const int b = bh >> 7, h = bh & 127;
  const int w0 = wseg * 64;
  const float g = gamma[0];
  for (int idx = tid; idx < CN * 64; idx += 256) {
    int c = idx >> 6, p = idx & 63;
    ts[c * 64 + p] = out[(((size_t)b * CN + c) * HN + h) * WN + w0 + p];
  }
  const int p0 = (tid & 15) * 4;
  const int cog = tid >> 4;  // 0..15
  for (int coc = 0; coc < CN; coc += 64) {
    __syncthreads();
    for (int idx = tid; idx < 64 * CN; idx += 256) {
      int co = idx >> 8, c = idx & 255;
      wvs[co * 260 + c] = Wv[(size_t)(coc + co) * CN + c];
    }
    __syncthreads();
    float acc[4][4] = {};
    for (int c0 = 0; c0 < CN; c0 += 4) {
      float ta[4][4];
#pragma unroll
      for (int a = 0; a < 4; ++a) {
        float4 v = *(const float4*)&ts[(c0 + a) * 64 + p0];
        ta[a][0] = v.x; ta[a][1] = v.y; ta[a][2] = v.z; ta[a][3] = v.w;
      }
#pragma unroll
      for (int rr = 0; rr < 4; ++rr) {
        float4 wv4 = *(const float4*)&wvs[(cog + 16 * rr) * 260 + c0];
        float wa[4] = {wv4.x, wv4.y, wv4.z, wv4.w};
#pragma unroll
        for (int p = 0; p < 4; ++p)
          acc[rr][p] += wa[0] * ta[0][p] + wa[1] * ta[1][p] + wa[2] * ta[2][p] + wa[3] * ta[3][p];
      }
    }
#pragma unroll
    for (int rr = 0; rr < 4; ++rr) {
      int co = coc + cog + 16 * rr;
      size_t base = (((size_t)b * CN + co) * HN + h) * WN + w0 + p0;
      float4 xv = *(const float4*)&x[base];
      float bbv = 2.0f * bv[co];
      float4 ov;
      ov.x = g * (acc[rr][0] + bbv) + xv.x;
      ov.y = g * (acc[rr][1] + bbv) + xv.y;
      ov.z = g * (acc[rr][2] + bbv) + xv.z;
      ov.w = g * (acc[rr][3] + bbv) + xv.w;
      *(float4*)&out[base] = ov;
    }
  }
}

extern "C" void kernel_launch(void* const* d_in, const int* in_sizes, int n_in,
                              void* d_out, int out_size, void* d_ws, size_t ws_size,
                              hipStream_t stream) {
  const float* x     = (const float*)d_in[0];
  const float* Wq    = (const float*)d_in[1];
  const float* bq    = (const float*)d_in[2];
  const float* Wk    = (const float*)d_in[3];
  const float* bk    = (const float*)d_in[4];
  const float* Wv    = (const float*)d_in[5];
  const float* bv    = (const float*)d_in[6];
  const float* gamma = (const float*)d_in[7];
  float* out = (float*)d_out;

  const size_t QSZ = (size_t)BN * CQn * HN * WN;  // 4,194,304
  const size_t XSZ = (size_t)BN * CN * HN * WN;   // 33,554,432
  bf16* wsb = (bf16*)d_ws;
  bf16* q   = wsb;
  bf16* k   = wsb + QSZ;
  bf16* qT  = wsb + 2 * QSZ;
  bf16* kT  = wsb + 3 * QSZ;
  bf16* xT  = wsb + 4 * QSZ;
  bf16* twP = wsb + 4 * QSZ + XSZ;
  bf16* Wvb = wsb + 4 * QSZ + 2 * XSZ;

  const size_t need_new = (4 * QSZ + 2 * XSZ + 65536) * sizeof(bf16);  // ~168 MB
  const size_t need_old = (4 * QSZ + XSZ) * sizeof(bf16);              // ~100.7 MB

  const int ATTN_LDS = (8192 + 160 * LST + 384) * 4;   // 118,784 B
  auto* fa_row_old = attn_1d<float, float, false, false>;
  auto* fa_row_pk  = attn_1d<float, bf16, false, true>;
  auto* fa_col     = attn_1d<bf16, bf16, true, false>;
  hipFuncSetAttribute((const void*)fa_row_old, hipFuncAttributeMaxDynamicSharedMemorySize, ATTN_LDS);
  hipFuncSetAttribute((const void*)fa_row_pk,  hipFuncAttributeMaxDynamicSharedMemorySize, ATTN_LDS);
  hipFuncSetAttribute((const void*)fa_col,     hipFuncAttributeMaxDynamicSharedMemorySize, ATTN_LDS);

  if (ws_size >= need_new) {
    proj_qk<<<BN * HN, 256, 0, stream>>>(x, Wq, bq, Wk, bk, q, k);
    transpose_bf16<bf16><<<2 * BN * CQn * 16, 256, 0, stream>>>(q, qT);
    transpose_bf16<float><<<BN * CN * 16, 256, 0, stream>>>(x, xT);
    wv_to_bf16<<<256, 256, 0, stream>>>(Wv, Wvb);
    // row attention -> t_w into twP (c8-packed bf16)
    fa_row_pk<<<BN * HN, 256, ATTN_LDS, stream>>>(q, k, x, twP);
    // column attention (transposed domain), in place on xT -> t_h^T
    fa_col<<<BN * WN, 256, ATTN_LDS, stream>>>(qT, kT, xT, xT);
    // twP += t_h (transposed back into packed layout)
    packed_merge<<<BN * 32 * 16, 256, 0, stream>>>(xT, twP);
    // out = gamma*(Wv@t + 2bv) + x via MFMA
    final_mfma<<<BN * HN, 512, 0, stream>>>(twP, Wvb, x, bv, gamma, out);
  } else if (ws_size >= need_old) {
    // fallback: round-1 flow
    const int FINAL_LDS = (16384 + 64 * 260) * 4;  // 132,096 B
    hipFuncSetAttribute((const void*)final_wv, hipFuncAttributeMaxDynamicSharedMemorySize, FINAL_LDS);
    proj_qk<<<BN * HN, 256, 0, stream>>>(x, Wq, bq, Wk, bk, q, k);
    transpose_bf16<bf16><<<2 * BN * CQn * 16, 256, 0, stream>>>(q, qT);
    transpose_bf16<float><<<BN * CN * 16, 256, 0, stream>>>(x, xT);
    fa_row_old<<<BN * HN, 256, ATTN_LDS, stream>>>(q, k, x, out);
    fa_col<<<BN * WN, 256, ATTN_LDS, stream>>>(qT, kT, xT, xT);
    transpose_add<<<BN * CN * 16, 256, 0, stream>>>(xT, out);
    final_wv<<<BN * HN * (WN / 64), 256, FINAL_LDS, stream>>>(out, x, Wv, bv, gamma);
  } else {
    hipMemsetAsync(d_out, 0x7f, (size_t)out_size * sizeof(float), stream);
  }
}

// Round 3
// 300.750 us; speedup vs baseline: 4.3182x; 2.5102x over previous
//
#include <hip/hip_runtime.h>
#include <hip/hip_bf16.h>

#define BN 8
#define CN 256
#define CQn 32
#define HN 128
#define WN 128
#define LST 132

using bf16 = __hip_bfloat16;
typedef short short8 __attribute__((ext_vector_type(8)));
typedef float f32x4 __attribute__((ext_vector_type(4)));

__device__ __forceinline__ float ldf(const float* p) { return *p; }
__device__ __forceinline__ float ldf(const bf16* p) { return __bfloat162float(*p); }
__device__ __forceinline__ void stf(float* p, float v) { *p = v; }
__device__ __forceinline__ void stf(bf16* p, float v) { *p = __float2bfloat16(v); }
__device__ __forceinline__ unsigned short f2bu(float v) {
  bf16 h = __float2bfloat16(v);
  return *(unsigned short*)&h;
}
__device__ __forceinline__ float bu2f(unsigned short u) {
  return __bfloat162float(*(const bf16*)&u);
}
__device__ __forceinline__ unsigned pack2(float a, float b) {
  return (unsigned)f2bu(a) | ((unsigned)f2bu(b) << 16);
}
__device__ __forceinline__ uint4 add8bf16(uint4 a, uint4 b) {
  union { uint4 v; unsigned short u[8]; } A, B, C;
  A.v = a; B.v = b;
#pragma unroll
  for (int e = 0; e < 8; ++e) C.u[e] = f2bu(bu2f(A.u[e]) + bu2f(B.u[e]));
  return C.v;
}

// ============================== NEW PATH ==============================

// ---- proj q,k -> pixel-major c-packed layout qF/kF[b][h][w][32c] bf16
__global__ __launch_bounds__(256) void proj_qk2(
    const float* __restrict__ x, const float* __restrict__ Wq, const float* __restrict__ bq,
    const float* __restrict__ Wk, const float* __restrict__ bk,
    bf16* __restrict__ qF, bf16* __restrict__ kF) {
  __shared__ float xs[64][128];
  __shared__ float wqs[CQn][64];
  __shared__ float wks[CQn][64];
  __shared__ float bqs[CQn], bks[CQn];
  const int tid = threadIdx.x;
  const int b = blockIdx.x >> 7, h = blockIdx.x & 127;
  if (tid < CQn) { bqs[tid] = bq[tid]; bks[tid] = bk[tid]; }
  const int w0 = (tid & 63) * 2;
  const int g = tid >> 6;  // 0..3
  float accq[8][2] = {};
  float acck[8][2] = {};
  for (int cc = 0; cc < CN; cc += 64) {
    __syncthreads();
    for (int idx = tid; idx < 64 * 128; idx += 256) {
      int c = idx >> 7, ww = idx & 127;
      xs[c][ww] = x[(((size_t)b * CN + cc + c) * HN + h) * WN + ww];
    }
    for (int idx = tid; idx < CQn * 64; idx += 256) {
      int oc = idx >> 6, c = idx & 63;
      wqs[oc][c] = Wq[oc * CN + cc + c];
      wks[oc][c] = Wk[oc * CN + cc + c];
    }
    __syncthreads();
    for (int c4 = 0; c4 < 64; c4 += 4) {
      float xa[4][2];
#pragma unroll
      for (int a = 0; a < 4; ++a) {
        float2 v = *(const float2*)&xs[c4 + a][w0];
        xa[a][0] = v.x; xa[a][1] = v.y;
      }
#pragma unroll
      for (int r = 0; r < 8; ++r) {
        float4 wq4 = *(const float4*)&wqs[g * 8 + r][c4];
        float4 wk4 = *(const float4*)&wks[g * 8 + r][c4];
        float wqa[4] = {wq4.x, wq4.y, wq4.z, wq4.w};
        float wka[4] = {wk4.x, wk4.y, wk4.z, wk4.w};
#pragma unroll
        for (int a = 0; a < 4; ++a) {
          accq[r][0] += wqa[a] * xa[a][0];
          accq[r][1] += wqa[a] * xa[a][1];
          acck[r][0] += wka[a] * xa[a][0];
          acck[r][1] += wka[a] * xa[a][1];
        }
      }
    }
  }
#pragma unroll
  for (int e = 0; e < 2; ++e) {
    union { unsigned short u[8]; uint4 v; } pq, pk;
#pragma unroll
    for (int rr = 0; rr < 8; ++rr) {
      int oc = g * 8 + rr;
      pq.u[rr] = f2bu(accq[rr][e] + bqs[oc]);
      pk.u[rr] = f2bu(acck[rr][e] + bks[oc]);
    }
    size_t base = (((size_t)b * 128 + h) * 128 + (w0 + e)) * 32 + g * 8;
    *(uint4*)&qF[base] = pq.v;
    *(uint4*)&kF[base] = pk.v;
  }
}

// ---- MFMA criss-cross 1D attention.
// COL=false: slice (b, h=r), attend along w; V = x fp32; out twP[b][cg][h=r][w=i][8]
// COL=true : slice (b, w=r), attend along h (+eye); V = xT bf16; out thP[b][cg][w=r][h=i][8]
template <bool COL>
__global__ __launch_bounds__(256) void attn_mfma(
    const bf16* __restrict__ qF, const bf16* __restrict__ kF,
    const void* __restrict__ vsrc, bf16* __restrict__ outP) {
  __shared__ unsigned short psm[128 * 128];  // P bf16, XOR-swizzled 16B slots
  __shared__ float rsum[128];
  const int tid = threadIdx.x;
  const int wid = tid >> 6;
  const int lane = tid & 63;
  const int l15 = lane & 15, lg = lane >> 4;
  const int b = blockIdx.x >> 7, r = blockIdx.x & 127;

  // ---- QK^T (swapped): D[j][i]; wave owns i-tiles {2wid,2wid+1}, all 8 j-tiles
  short8 qf[2];
  const int ti0 = wid * 2;
#pragma unroll
  for (int t2 = 0; t2 < 2; ++t2) {
    int i = (ti0 + t2) * 16 + l15;
    size_t base = COL ? (((size_t)b * 128 + i) * 128 + r) * 32
                      : (((size_t)b * 128 + r) * 128 + i) * 32;
    qf[t2] = *(const short8*)&qF[base + lg * 8];
  }
  f32x4 lgt[2][8];
#pragma unroll
  for (int t2 = 0; t2 < 2; ++t2)
#pragma unroll
    for (int tj = 0; tj < 8; ++tj)
#pragma unroll
      for (int e = 0; e < 4; ++e) lgt[t2][tj][e] = 0.f;
#pragma unroll
  for (int tj = 0; tj < 8; ++tj) {
    int j = tj * 16 + l15;
    size_t base = COL ? (((size_t)b * 128 + j) * 128 + r) * 32
                      : (((size_t)b * 128 + r) * 128 + j) * 32;
    short8 kf = *(const short8*)&kF[base + lg * 8];
#pragma unroll
    for (int t2 = 0; t2 < 2; ++t2)
      lgt[t2][tj] = __builtin_amdgcn_mfma_f32_16x16x32_bf16(kf, qf[t2], lgt[t2][tj], 0, 0, 0);
  }

  // ---- softmax over j (lane's j = tj*16 + lg*4 + rr at fixed i)
#pragma unroll
  for (int t2 = 0; t2 < 2; ++t2) {
    const int i = (ti0 + t2) * 16 + l15;
    if (COL) {
#pragma unroll
      for (int tj = 0; tj < 8; ++tj)
#pragma unroll
        for (int rr = 0; rr < 4; ++rr)
          if (tj * 16 + lg * 4 + rr == i) lgt[t2][tj][rr] += 1.0f;
    }
    float m = -1e30f;
#pragma unroll
    for (int tj = 0; tj < 8; ++tj)
#pragma unroll
      for (int rr = 0; rr < 4; ++rr) m = fmaxf(m, lgt[t2][tj][rr]);
    m = fmaxf(m, __shfl_xor(m, 16, 64));
    m = fmaxf(m, __shfl_xor(m, 32, 64));
    float s = 0.f;
#pragma unroll
    for (int tj = 0; tj < 8; ++tj)
#pragma unroll
      for (int rr = 0; rr < 4; ++rr) {
        float e = __expf(lgt[t2][tj][rr] - m);
        lgt[t2][tj][rr] = e;
        s += e;
      }
    s += __shfl_xor(s, 16, 64);
    s += __shfl_xor(s, 32, 64);
    if (lg == 0) rsum[i] = s;
#pragma unroll
    for (int tj = 0; tj < 8; ++tj) {
      int slot = ((tj * 2) + (lg >> 1)) ^ (i & 7);
      int elem = i * 128 + slot * 8 + (lg & 1) * 4;
      uint2 v;
      v.x = pack2(lgt[t2][tj][0], lgt[t2][tj][1]);
      v.y = pack2(lgt[t2][tj][2], lgt[t2][tj][3]);
      *(uint2*)&psm[elem] = v;
    }
  }
  __syncthreads();

  // ---- PV: D[c][i] = sum_j V[c][j] P[i][j]
  float rinv[8];
#pragma unroll
  for (int nt = 0; nt < 8; ++nt) rinv[nt] = 1.0f / rsum[nt * 16 + l15];

  const int cbase = wid * 64;
  const float* xf = (const float*)vsrc;
  const bf16* xb = (const bf16*)vsrc;
  unsigned short* ou = (unsigned short*)outP;
#pragma unroll
  for (int cp = 0; cp < 2; ++cp) {
    short8 vf[2][4];
#pragma unroll
    for (int u = 0; u < 2; ++u) {
      int c = cbase + (cp * 2 + u) * 16 + l15;
#pragma unroll
      for (int ks = 0; ks < 4; ++ks) {
        if (COL) {
          vf[u][ks] = *(const short8*)&xb[(((size_t)b * 256 + c) * 128 + r) * 128 + ks * 32 + lg * 8];
        } else {
          const float* xp = &xf[((size_t)b * 256 + c) * 16384 + r * 128 + ks * 32 + lg * 8];
          float4 f0 = *(const float4*)xp;
          float4 f1 = *(const float4*)(xp + 4);
          union { unsigned short u16[8]; short8 s8; } tmp;
          tmp.u16[0] = f2bu(f0.x); tmp.u16[1] = f2bu(f0.y);
          tmp.u16[2] = f2bu(f0.z); tmp.u16[3] = f2bu(f0.w);
          tmp.u16[4] = f2bu(f1.x); tmp.u16[5] = f2bu(f1.y);
          tmp.u16[6] = f2bu(f1.z); tmp.u16[7] = f2bu(f1.w);
          vf[u][ks] = tmp.s8;
        }
      }
    }
    f32x4 acc[2][8];
#pragma unroll
    for (int u = 0; u < 2; ++u)
#pragma unroll
      for (int nt = 0; nt < 8; ++nt)
#pragma unroll
        for (int e = 0; e < 4; ++e) acc[u][nt][e] = 0.f;
#pragma unroll
    for (int ks = 0; ks < 4; ++ks)
#pragma unroll
      for (int nt = 0; nt < 8; ++nt) {
        int i = nt * 16 + l15;
        short8 pf = *(const short8*)&psm[i * 128 + (((ks * 4) + lg) ^ (i & 7)) * 8];
#pragma unroll
        for (int u = 0; u < 2; ++u)
          acc[u][nt] = __builtin_amdgcn_mfma_f32_16x16x32_bf16(vf[u][ks], pf, acc[u][nt], 0, 0, 0);
      }
#pragma unroll
    for (int u = 0; u < 2; ++u) {
      int ct = cp * 2 + u;
      int cg = wid * 8 + ct * 2 + (lg >> 1);
#pragma unroll
      for (int nt = 0; nt < 8; ++nt) {
        int i = nt * 16 + l15;
        float sc = rinv[nt];
        uint2 v;
        v.x = pack2(acc[u][nt][0] * sc, acc[u][nt][1] * sc);
        v.y = pack2(acc[u][nt][2] * sc, acc[u][nt][3] * sc);
        size_t elem = ((((size_t)b * 32 + cg) * 128 + r) * 128 + i) * 8 + (lg & 1) * 4;
        *(uint2*)&ou[elem] = v;
      }
    }
  }
}

// ---- twP[b][cg][h][w][8] += thP[b][cg][w][h][8]  (uint4 = 8 bf16 payloads)
__global__ __launch_bounds__(256) void packed_merge2(const bf16* __restrict__ thP,
                                                     bf16* __restrict__ twP) {
  __shared__ uint4 ts[32][33];
  const int tid = threadIdx.x;
  const int blk = blockIdx.x;
  const int tI = blk & 15;
  const int cg = (blk >> 4) & 31;
  const int b = blk >> 9;
  const int h0 = (tI >> 2) * 32, w0 = (tI & 3) * 32;
  const uint4* tp = (const uint4*)thP;
  uint4* tw = (uint4*)twP;
#pragma unroll
  for (int rep = 0; rep < 4; ++rep) {
    int cell = rep * 256 + tid;
    int ww = cell >> 5, hh = cell & 31;
    ts[ww][hh] = tp[(((size_t)b * 32 + cg) * 128 + (w0 + ww)) * 128 + (h0 + hh)];
  }
  __syncthreads();
#pragma unroll
  for (int rep = 0; rep < 4; ++rep) {
    int cell = rep * 256 + tid;
    int hh = cell >> 5, ww = cell & 31;
    size_t o = (((size_t)b * 32 + cg) * 128 + (h0 + hh)) * 128 + (w0 + ww);
    tw[o] = add8bf16(tw[o], ts[ww][hh]);
  }
}

// ============================== SHARED / FALLBACK ==============================

// transpose [p][r][c] -> [p][c][r], out bf16
template <typename TIn>
__global__ __launch_bounds__(256) void transpose_bf16(const TIn* __restrict__ in,
                                                      bf16* __restrict__ out) {
  __shared__ float tile[32][33];
  const int blk = blockIdx.x;
  const int p = blk >> 4, t = blk & 15;
  const int r0 = (t >> 2) * 32, c0 = (t & 3) * 32;
  const int tx = threadIdx.x & 31, ty = threadIdx.x >> 5;
  const TIn* ip = in + (size_t)p * 128 * 128;
#pragma unroll
  for (int rr = 0; rr < 4; ++rr)
    tile[ty + 8 * rr][tx] = ldf(&ip[(r0 + ty + 8 * rr) * 128 + c0 + tx]);
  __syncthreads();
  bf16* op = out + (size_t)p * 128 * 128;
#pragma unroll
  for (int rr = 0; rr < 4; ++rr)
    op[(c0 + ty + 8 * rr) * 128 + r0 + tx] = __float2bfloat16(tile[tx][ty + 8 * rr]);
}

__global__ __launch_bounds__(256) void wv_to_bf16(const float* __restrict__ Wv,
                                                  bf16* __restrict__ Wvb) {
  int i = blockIdx.x * 256 + threadIdx.x;
  Wvb[i] = __float2bfloat16(Wv[i]);
}

// ---- OLD proj (fallback): q/k [b][c][h][w]
__global__ __launch_bounds__(256) void proj_qk(
    const float* __restrict__ x, const float* __restrict__ Wq, const float* __restrict__ bq,
    const float* __restrict__ Wk, const float* __restrict__ bk,
    bf16* __restrict__ q, bf16* __restrict__ k) {
  __shared__ float xs[64][128];
  __shared__ float wqs[CQn][64];
  __shared__ float wks[CQn][64];
  __shared__ float bqs[CQn], bks[CQn];
  const int tid = threadIdx.x;
  const int b = blockIdx.x >> 7, h = blockIdx.x & 127;
  if (tid < CQn) { bqs[tid] = bq[tid]; bks[tid] = bk[tid]; }
  const int w0 = (tid & 63) * 2;
  const int g = tid >> 6;
  float accq[8][2] = {};
  float acck[8][2] = {};
  for (int cc = 0; cc < CN; cc += 64) {
    __syncthreads();
    for (int idx = tid; idx < 64 * 128; idx += 256) {
      int c = idx >> 7, ww = idx & 127;
      xs[c][ww] = x[(((size_t)b * CN + cc + c) * HN + h) * WN + ww];
    }
    for (int idx = tid; idx < CQn * 64; idx += 256) {
      int oc = idx >> 6, c = idx & 63;
      wqs[oc][c] = Wq[oc * CN + cc + c];
      wks[oc][c] = Wk[oc * CN + cc + c];
    }
    __syncthreads();
    for (int c4 = 0; c4 < 64; c4 += 4) {
      float xa[4][2];
#pragma unroll
      for (int a = 0; a < 4; ++a) {
        float2 v = *(const float2*)&xs[c4 + a][w0];
        xa[a][0] = v.x; xa[a][1] = v.y;
      }
#pragma unroll
      for (int r = 0; r < 8; ++r) {
        float4 wq4 = *(const float4*)&wqs[g * 8 + r][c4];
        float4 wk4 = *(const float4*)&wks[g * 8 + r][c4];
        float wqa[4] = {wq4.x, wq4.y, wq4.z, wq4.w};
        float wka[4] = {wk4.x, wk4.y, wk4.z, wk4.w};
#pragma unroll
        for (int a = 0; a < 4; ++a) {
          accq[r][0] += wqa[a] * xa[a][0];
          accq[r][1] += wqa[a] * xa[a][1];
          acck[r][0] += wka[a] * xa[a][0];
          acck[r][1] += wka[a] * xa[a][1];
        }
      }
    }
  }
#pragma unroll
  for (int r = 0; r < 8; ++r) {
    int oc = g * 8 + r;
    size_t off = (((size_t)b * CQn + oc) * HN + h) * WN + w0;
    q[off]     = __float2bfloat16(accq[r][0] + bqs[oc]);
    q[off + 1] = __float2bfloat16(accq[r][1] + bqs[oc]);
    k[off]     = __float2bfloat16(acck[r][0] + bks[oc]);
    k[off + 1] = __float2bfloat16(acck[r][1] + bks[oc]);
  }
}

// ---- OLD VALU attention (fallback)
template <typename XT, typename OT, bool ADD_EYE, bool PACKED>
__global__ __launch_bounds__(256) void attn_1d(
    const bf16* __restrict__ qsrc, const bf16* __restrict__ ksrc,
    const XT* __restrict__ xsrc, OT* __restrict__ outp) {
  extern __shared__ float sm[];
  float* qs  = sm;
  float* ks  = sm + 4096;
  float* Ls  = sm + 8192;
  float* xsv = sm + 8192 + 128 * LST;
  float* red = sm + 8192 + 160 * LST;
  float* rsum = sm + 8192 + 160 * LST + 256;
  const int tid = threadIdx.x;
  const int b = blockIdx.x >> 7, r = blockIdx.x & 127;

  for (int idx = tid; idx < CQn * 128; idx += 256) {
    int c = idx >> 7, j = idx & 127;
    size_t off = (((size_t)b * CQn + c) * 128 + r) * 128 + j;
    qs[idx] = __bfloat162float(qsrc[off]);
    ks[idx] = __bfloat162float(ksrc[off]);
  }
  __syncthreads();
#pragma unroll
  for (int g = 0; g < 4; ++g) {
    int t = tid + g * 256;
    int i0 = (t >> 5) * 4, j0 = (t & 31) * 4;
    float acc[4][4] = {};
    for (int c = 0; c < CQn; ++c) {
      float4 qv = *(const float4*)&qs[c * 128 + i0];
      float4 kv = *(const float4*)&ks[c * 128 + j0];
      float qa[4] = {qv.x, qv.y, qv.z, qv.w};
      float ka[4] = {kv.x, kv.y, kv.z, kv.w};
#pragma unroll
      for (int ii = 0; ii < 4; ++ii)
#pragma unroll
        for (int jj = 0; jj < 4; ++jj) acc[ii][jj] += qa[ii] * ka[jj];
    }
#pragma unroll
    for (int ii = 0; ii < 4; ++ii) {
      if (ADD_EYE) {
        int i = i0 + ii;
        if (i >= j0 && i < j0 + 4) acc[ii][i - j0] += 1.0f;
      }
      float4 o = make_float4(acc[ii][0], acc[ii][1], acc[ii][2], acc[ii][3]);
      *(float4*)&Ls[(i0 + ii) * LST + j0] = o;
    }
  }
  __syncthreads();
  {
    const int row = tid & 127, jb = (tid >> 7) * 64;
    float m = -1e30f;
    for (int j = 0; j < 64; ++j) m = fmaxf(m, Ls[row * LST + jb + j]);
    red[tid] = m;
    __syncthreads();
    m = fmaxf(red[row], red[row + 128]);
    float s = 0.f;
    for (int j = 0; j < 64; ++j) {
      float e = __expf(Ls[row * LST + jb + j] - m);
      Ls[row * LST + jb + j] = e;
      s += e;
    }
    __syncthreads();
    red[tid] = s;
    __syncthreads();
    if (tid < 128) rsum[tid] = red[tid] + red[tid + 128];
  }
  const int ci0 = (tid >> 5) * 4;
  const int il = tid & 31;
  float rinv[4];
  __syncthreads();
#pragma unroll
  for (int a = 0; a < 4; ++a) rinv[a] = 1.0f / rsum[il + 32 * a];

  for (int cc0 = 0; cc0 < CN; cc0 += 32) {
    __syncthreads();
    for (int idx = tid; idx < 32 * 128; idx += 256) {
      int c = idx >> 7, j = idx & 127;
      xsv[c * LST + j] = ldf(&xsrc[(((size_t)b * CN + cc0 + c) * 128 + r) * 128 + j]);
    }
    __syncthreads();
    float acc[4][4] = {};
    for (int j0 = 0; j0 < 128; j0 += 4) {
      float xa[4][4], pa[4][4];
#pragma unroll
      for (int ci = 0; ci < 4; ++ci) {
        float4 v = *(const float4*)&xsv[(ci0 + ci) * LST + j0];
        xa[ci][0] = v.x; xa[ci][1] = v.y; xa[ci][2] = v.z; xa[ci][3] = v.w;
      }
#pragma unroll
      for (int a = 0; a < 4; ++a) {
        float4 v = *(const float4*)&Ls[(il + 32 * a) * LST + j0];
        pa[a][0] = v.x; pa[a][1] = v.y; pa[a][2] = v.z; pa[a][3] = v.w;
      }
#pragma unroll
      for (int ci = 0; ci < 4; ++ci)
#pragma unroll
        for (int a = 0; a < 4; ++a)
          acc[ci][a] += xa[ci][0] * pa[a][0] + xa[ci][1] * pa[a][1] +
                        xa[ci][2] * pa[a][2] + xa[ci][3] * pa[a][3];
    }
    if constexpr (PACKED) {
      __syncthreads();
      unsigned short* xu = (unsigned short*)xsv;
#pragma unroll
      for (int ci = 0; ci < 4; ++ci)
#pragma unroll
        for (int a = 0; a < 4; ++a)
          xu[(ci0 + ci) * 132 + il + 32 * a] = f2bu(acc[ci][a] * rinv[a]);
      __syncthreads();
      unsigned short* ou = (unsigned short*)outp;
#pragma unroll
      for (int p = 0; p < 2; ++p) {
        int idx = p * 256 + tid;
        int cgL = idx >> 7, px = idx & 127;
        unsigned short tmp[8];
#pragma unroll
        for (int e = 0; e < 8; ++e) tmp[e] = xu[(cgL * 8 + e) * 132 + px];
        size_t g16 = (((size_t)b * 32 + (cc0 >> 3) + cgL) * 128 + r) * 128 + px;
        *(uint4*)&ou[g16 * 8] = *(const uint4*)tmp;
      }
    } else {
#pragma unroll
      for (int ci = 0; ci < 4; ++ci) {
        size_t base = (((size_t)b * CN + cc0 + ci0 + ci) * 128 + r) * 128 + il;
#pragma unroll
        for (int a = 0; a < 4; ++a) stf(&outp[base + 32 * a], acc[ci][a] * rinv[a]);
      }
    }
  }
}

// ---- OLD merge (fallback): twP[b][cg][h][w][8] += t_hT[b][c][w][h]
__global__ __launch_bounds__(256) void packed_merge(const bf16* __restrict__ thT,
                                                    bf16* __restrict__ twP) {
  __shared__ unsigned short ths[8 * 32 * 36];
  const int tid = threadIdx.x;
  const int blk = blockIdx.x;
  const int tI = blk & 15;
  const int cgI = (blk >> 4) & 31;
  const int b = blk >> 9;
  const int w0 = (tI >> 2) * 32, h0 = (tI & 3) * 32;
  {
    const int e = tid >> 5, ww = tid & 31;
    const unsigned short* src = (const unsigned short*)(thT +
        ((((size_t)b * 256 + cgI * 8 + e) * 128) + (w0 + ww)) * 128 + h0);
    unsigned short* dst = &ths[(e * 32 + ww) * 36];
#pragma unroll
    for (int j = 0; j < 8; ++j)
      *(uint2*)&dst[j * 4] = *(const uint2*)&src[j * 4];
  }
  __syncthreads();
  unsigned short* twu = (unsigned short*)twP;
#pragma unroll
  for (int rep = 0; rep < 4; ++rep) {
    int cell = rep * 256 + tid;
    int hh = cell >> 5, ww = cell & 31;
    size_t g16 = ((((size_t)b * 32 + cgI) * 128) + h0 + hh) * 128 + (w0 + ww);
    uint4 cur = *(const uint4*)&twu[g16 * 8];
    unsigned short cu[8];
    *(uint4*)cu = cur;
#pragma unroll
    for (int e = 0; e < 8; ++e)
      cu[e] = f2bu(bu2f(cu[e]) + bu2f(ths[(e * 32 + ww) * 36 + hh]));
    *(uint4*)&twu[g16 * 8] = *(const uint4*)cu;
  }
}

// ---- final MFMA GEMM: out = gamma*(Wv @ t + 2bv) + x, t from twP
__global__ __launch_bounds__(512) void final_mfma(
    const bf16* __restrict__ twP, const bf16* __restrict__ Wvb,
    const float* __restrict__ x, const float* __restrict__ bv,
    const float* __restrict__ gamma, float* __restrict__ out) {
  __shared__ short As[256][64];
  __shared__ short Bs[128][64];
  const int tid = threadIdx.x;
  const int b = blockIdx.x >> 7, h = blockIdx.x & 127;
  const int lane = tid & 63;
  const int wid = tid >> 6;
  const int wm = wid >> 1, wn = wid & 1;
  const int l15 = lane & 15, lg = lane >> 4;
  const unsigned short* twu = (const unsigned short*)twP;

  f32x4 acc[4][4];
#pragma unroll
  for (int m = 0; m < 4; ++m)
#pragma unroll
    for (int n = 0; n < 4; ++n)
#pragma unroll
      for (int e = 0; e < 4; ++e) acc[m][n][e] = 0.f;

  for (int k0 = 0; k0 < 256; k0 += 64) {
    __syncthreads();
#pragma unroll
    for (int p = 0; p < 4; ++p) {
      int idx = p * 512 + tid;
      int co = idx >> 3, cg = idx & 7;
      uint4 v = *(const uint4*)&Wvb[(size_t)co * 256 + k0 + cg * 8];
      *(uint4*)&As[co][(cg ^ (co & 7)) * 8] = v;
    }
#pragma unroll
    for (int p = 0; p < 2; ++p) {
      int idx = p * 512 + tid;
      int w = idx & 127, cgL = idx >> 7;
      size_t g16 = (((size_t)b * 32 + (k0 >> 3) + cgL) * 128 + h) * 128 + w;
      uint4 v = *(const uint4*)&twu[g16 * 8];
      *(uint4*)&Bs[w][(cgL ^ (w & 7)) * 8] = v;
    }
    __syncthreads();
    short8 a[4][2], bb[4][2];
#pragma unroll
    for (int m = 0; m < 4; ++m)
#pragma unroll
      for (int kk = 0; kk < 2; ++kk) {
        int co = wm * 64 + m * 16 + l15;
        int cg = kk * 4 + lg;
        a[m][kk] = *(const short8*)&As[co][(cg ^ (co & 7)) * 8];
      }
#pragma unroll
    for (int n = 0; n < 4; ++n)
#pragma unroll
      for (int kk = 0; kk < 2; ++kk) {
        int w = wn * 64 + n * 16 + l15;
        int cg = kk * 4 + lg;
        bb[n][kk] = *(const short8*)&Bs[w][(cg ^ (w & 7)) * 8];
      }
#pragma unroll
    for (int kk = 0; kk < 2; ++kk)
#pragma unroll
      for (int m = 0; m < 4; ++m)
#pragma unroll
        for (int n = 0; n < 4; ++n)
          acc[m][n] = __builtin_amdgcn_mfma_f32_16x16x32_bf16(a[m][kk], bb[n][kk], acc[m][n], 0, 0, 0);
  }

  const float g = gamma[0];
  float bvv[4][4];
#pragma unroll
  for (int m = 0; m < 4; ++m)
#pragma unroll
    for (int rr = 0; rr < 4; ++rr)
      bvv[m][rr] = 2.0f * bv[wm * 64 + m * 16 + lg * 4 + rr];
#pragma unroll
  for (int m = 0; m < 4; ++m)
#pragma unroll
    for (int n = 0; n < 4; ++n) {
      int w = wn * 64 + n * 16 + l15;
#pragma unroll
      for (int rr = 0; rr < 4; ++rr) {
        int co = wm * 64 + m * 16 + lg * 4 + rr;
        size_t o = (((size_t)b * 256 + co) * 128 + h) * 128 + w;
        out[o] = g * (acc[m][n][rr] + bvv[m][rr]) + x[o];
      }
    }
}

extern "C" void kernel_launch(void* const* d_in, const int* in_sizes, int n_in,
                              void* d_out, int out_size, void* d_ws, size_t ws_size,
                              hipStream_t stream) {
  const float* x     = (const float*)d_in[0];
  const float* Wq    = (const float*)d_in[1];
  const float* bq    = (const float*)d_in[2];
  const float* Wk    = (const float*)d_in[3];
  const float* bk    = (const float*)d_in[4];
  const float* Wv    = (const float*)d_in[5];
  const float* bv    = (const float*)d_in[6];
  const float* gamma = (const float*)d_in[7];
  float* out = (float*)d_out;

  const size_t QSZ = (size_t)BN * CQn * HN * WN;  // 4,194,304
  const size_t XSZ = (size_t)BN * CN * HN * WN;   // 33,554,432
  bf16* wsb = (bf16*)d_ws;

  const size_t need3 = (2 * QSZ + 3 * XSZ + 65536) * sizeof(bf16);  // ~218 MB
  const size_t need2 = (4 * QSZ + 2 * XSZ + 65536) * sizeof(bf16);  // ~168 MB

  if (ws_size >= need3) {
    bf16* qF  = wsb;
    bf16* kF  = wsb + QSZ;
    bf16* xT  = wsb + 2 * QSZ;
    bf16* twP = wsb + 2 * QSZ + XSZ;
    bf16* thP = wsb + 2 * QSZ + 2 * XSZ;
    bf16* Wvb = wsb + 2 * QSZ + 3 * XSZ;
    proj_qk2<<<BN * HN, 256, 0, stream>>>(x, Wq, bq, Wk, bk, qF, kF);
    transpose_bf16<float><<<BN * CN * 16, 256, 0, stream>>>(x, xT);
    wv_to_bf16<<<256, 256, 0, stream>>>(Wv, Wvb);
    attn_mfma<false><<<BN * HN, 256, 0, stream>>>(qF, kF, (const void*)x, twP);
    attn_mfma<true><<<BN * WN, 256, 0, stream>>>(qF, kF, (const void*)xT, thP);
    packed_merge2<<<BN * 32 * 16, 256, 0, stream>>>(thP, twP);
    final_mfma<<<BN * HN, 512, 0, stream>>>(twP, Wvb, x, bv, gamma, out);
  } else if (ws_size >= need2) {
    bf16* q   = wsb;
    bf16* k   = wsb + QSZ;
    bf16* qT  = wsb + 2 * QSZ;
    bf16* kT  = wsb + 3 * QSZ;
    bf16* xT  = wsb + 4 * QSZ;
    bf16* twP = wsb + 4 * QSZ + XSZ;
    bf16* Wvb = wsb + 4 * QSZ + 2 * XSZ;
    const int ATTN_LDS = (8192 + 160 * LST + 384) * 4;
    auto* fa_row_pk = attn_1d<float, bf16, false, true>;
    auto* fa_col    = attn_1d<bf16, bf16, true, false>;
    hipFuncSetAttribute((const void*)fa_row_pk, hipFuncAttributeMaxDynamicSharedMemorySize, ATTN_LDS);
    hipFuncSetAttribute((const void*)fa_col,    hipFuncAttributeMaxDynamicSharedMemorySize, ATTN_LDS);
    proj_qk<<<BN * HN, 256, 0, stream>>>(x, Wq, bq, Wk, bk, q, k);
    transpose_bf16<bf16><<<2 * BN * CQn * 16, 256, 0, stream>>>(q, qT);
    transpose_bf16<float><<<BN * CN * 16, 256, 0, stream>>>(x, xT);
    wv_to_bf16<<<256, 256, 0, stream>>>(Wv, Wvb);
    fa_row_pk<<<BN * HN, 256, ATTN_LDS, stream>>>(q, k, x, twP);
    fa_col<<<BN * WN, 256, ATTN_LDS, stream>>>(qT, kT, xT, xT);
    packed_merge<<<BN * 32 * 16, 256, 0, stream>>>(xT, twP);
    final_mfma<<<BN * HN, 512, 0, stream>>>(twP, Wvb, x, bv, gamma, out);
  } else {
    hipMemsetAsync(d_out, 0x7f, (size_t)out_size * sizeof(float), stream);
  }
}

// Round 5
// 246.357 us; speedup vs baseline: 5.2717x; 1.2208x over previous
//
#include <hip/hip_runtime.h>
#include <hip/hip_bf16.h>

#define BN 8
#define CN 256
#define CQn 32
#define HN 128
#define WN 128

using bf16 = __hip_bfloat16;
typedef short short8 __attribute__((ext_vector_type(8)));
typedef float f32x4 __attribute__((ext_vector_type(4)));

__device__ __forceinline__ float ldf(const float* p) { return *p; }
__device__ __forceinline__ float ldf(const bf16* p) { return __bfloat162float(*p); }
__device__ __forceinline__ unsigned short f2bu(float v) {
  bf16 h = __float2bfloat16(v);
  return *(unsigned short*)&h;
}
__device__ __forceinline__ float bu2f(unsigned short u) {
  return __bfloat162float(*(const bf16*)&u);
}
__device__ __forceinline__ unsigned pack2(float a, float b) {
  return (unsigned)f2bu(a) | ((unsigned)f2bu(b) << 16);
}
__device__ __forceinline__ uint4 add8bf16(uint4 a, uint4 b) {
  union { uint4 v; unsigned short u[8]; } A, B, C;
  A.v = a; B.v = b;
#pragma unroll
  for (int e = 0; e < 8; ++e) C.u[e] = f2bu(bu2f(A.u[e]) + bu2f(B.u[e]));
  return C.v;
}

// ---- MFMA projection: qF/kF[b][h][w][32c] bf16, plus xbf[b][c][h][w] bf16 copy of x.
// Block = (b, h, w-half). M=64 (32 q oc + 32 k oc), N=64 (w-half), K=256 (c).
// Static LDS = 32768 (xs) + 32768 (Ws) = 65536 B exactly.
__global__ __launch_bounds__(256) void proj_qk3(
    const float* __restrict__ x, const float* __restrict__ Wq, const float* __restrict__ bq,
    const float* __restrict__ Wk, const float* __restrict__ bk,
    bf16* __restrict__ qF, bf16* __restrict__ kF, bf16* __restrict__ xbf) {
  __shared__ unsigned short xs[256 * 64];   // [c][w-local]; row=128B -> col reads 2-way (free)
  __shared__ unsigned short Ws[64 * 256];   // [oc][c], 16B-chunk swizzle slot = cg ^ (oc&7)
  const int tid = threadIdx.x;
  const int half = blockIdx.x & 1;
  const int bh = blockIdx.x >> 1;
  const int b = bh >> 7, h = bh & 127;
  const int w0 = half * 64;

  // stage Ws: 64 oc x 32 chunks (cg) of 8 channels = 2048 chunks
#pragma unroll
  for (int it = 0; it < 8; ++it) {
    int idx = it * 256 + tid;           // 0..2047
    int oc = idx >> 5, cg = idx & 31;
    const float* wp = (oc < 32) ? &Wq[(size_t)oc * 256 + cg * 8]
                                : &Wk[(size_t)(oc - 32) * 256 + cg * 8];
    float4 f0 = *(const float4*)wp;
    float4 f1 = *(const float4*)(wp + 4);
    union { unsigned short u[8]; uint4 v; } t;
    t.u[0] = f2bu(f0.x); t.u[1] = f2bu(f0.y); t.u[2] = f2bu(f0.z); t.u[3] = f2bu(f0.w);
    t.u[4] = f2bu(f1.x); t.u[5] = f2bu(f1.y); t.u[6] = f2bu(f1.z); t.u[7] = f2bu(f1.w);
    *(uint4*)&Ws[oc * 256 + (cg ^ (oc & 7)) * 8] = t.v;
  }
  // stage xs (and emit xbf): 256 c x 16 w-chunks of 4
  unsigned short* xbu = (unsigned short*)xbf;
#pragma unroll
  for (int it = 0; it < 16; ++it) {
    int idx = it * 256 + tid;           // 0..4095
    int c = idx >> 4, wc = idx & 15;
    size_t gix = (((size_t)b * 256 + c) * 128 + h) * 128 + w0 + wc * 4;
    float4 f = *(const float4*)&x[gix];
    union { unsigned short u[4]; uint2 v; } t;
    t.u[0] = f2bu(f.x); t.u[1] = f2bu(f.y); t.u[2] = f2bu(f.z); t.u[3] = f2bu(f.w);
    *(uint2*)&xs[c * 64 + wc * 4] = t.v;
    *(uint2*)&xbu[gix] = t.v;
  }
  __syncthreads();

  const int lane = tid & 63, wid = tid >> 6;  // 4 waves, each owns 16 w
  const int l15 = lane & 15, lg = lane >> 4;
  f32x4 acc[4];
#pragma unroll
  for (int mt = 0; mt < 4; ++mt)
#pragma unroll
    for (int e = 0; e < 4; ++e) acc[mt][e] = 0.f;

#pragma unroll
  for (int ks = 0; ks < 8; ++ks) {
    union { unsigned short u[8]; short8 s; } bf;
#pragma unroll
    for (int e = 0; e < 8; ++e)
      bf.u[e] = xs[(ks * 32 + lg * 8 + e) * 64 + wid * 16 + l15];
#pragma unroll
    for (int mt = 0; mt < 4; ++mt) {
      int oc = mt * 16 + l15;
      short8 af = *(const short8*)&Ws[oc * 256 + ((ks * 4 + lg) ^ (oc & 7)) * 8];
      acc[mt] = __builtin_amdgcn_mfma_f32_16x16x32_bf16(af, bf.s, acc[mt], 0, 0, 0);
    }
  }

  const int w = w0 + wid * 16 + l15;
#pragma unroll
  for (int mt = 0; mt < 4; ++mt) {
    float bb[4];
#pragma unroll
    for (int rr = 0; rr < 4; ++rr) {
      int ch = (mt & 1) * 16 + lg * 4 + rr;
      bb[rr] = (mt < 2) ? bq[ch] : bk[ch];
    }
    uint2 v;
    v.x = pack2(acc[mt][0] + bb[0], acc[mt][1] + bb[1]);
    v.y = pack2(acc[mt][2] + bb[2], acc[mt][3] + bb[3]);
    size_t base = (((size_t)b * 128 + h) * 128 + w) * 32 + (mt & 1) * 16 + lg * 4;
    if (mt < 2) *(uint2*)&((unsigned short*)qF)[base] = v;
    else        *(uint2*)&((unsigned short*)kF)[base] = v;
  }
}

// ---- transpose [p][r][c] -> [p][c][r], bf16 -> bf16
template <typename TIn>
__global__ __launch_bounds__(256) void transpose_bf16(const TIn* __restrict__ in,
                                                      bf16* __restrict__ out) {
  __shared__ float tile[32][33];
  const int blk = blockIdx.x;
  const int p = blk >> 4, t = blk & 15;
  const int r0 = (t >> 2) * 32, c0 = (t & 3) * 32;
  const int tx = threadIdx.x & 31, ty = threadIdx.x >> 5;
  const TIn* ip = in + (size_t)p * 128 * 128;
#pragma unroll
  for (int rr = 0; rr < 4; ++rr)
    tile[ty + 8 * rr][tx] = ldf(&ip[(r0 + ty + 8 * rr) * 128 + c0 + tx]);
  __syncthreads();
  bf16* op = out + (size_t)p * 128 * 128;
#pragma unroll
  for (int rr = 0; rr < 4; ++rr)
    op[(c0 + ty + 8 * rr) * 128 + r0 + tx] = __float2bfloat16(tile[tx][ty + 8 * rr]);
}

__global__ __launch_bounds__(256) void wv_to_bf16(const float* __restrict__ Wv,
                                                  bf16* __restrict__ Wvb) {
  int i = blockIdx.x * 256 + threadIdx.x;
  Wvb[i] = __float2bfloat16(Wv[i]);
}

// ---- MFMA criss-cross 1D attention (V source bf16).
// COL=false: slice (b, h=r), attend along w; V = xbf[b][c][h][w]; out twP[b][cg][h=r][w=i][8]
// COL=true : slice (b, w=r), attend along h (+eye); V = xT[b][c][w][h]; out thP[b][cg][w=r][h=i][8]
template <bool COL>
__global__ __launch_bounds__(256) void attn_mfma(
    const bf16* __restrict__ qF, const bf16* __restrict__ kF,
    const bf16* __restrict__ vsrc, bf16* __restrict__ outP) {
  __shared__ unsigned short psm[128 * 128];  // P bf16, XOR-swizzled 16B slots
  __shared__ float rsum[128];
  const int tid = threadIdx.x;
  const int wid = tid >> 6;
  const int lane = tid & 63;
  const int l15 = lane & 15, lg = lane >> 4;
  const int b = blockIdx.x >> 7, r = blockIdx.x & 127;

  // ---- QK^T (swapped): D[j][i]; wave owns i-tiles {2wid,2wid+1}, all 8 j-tiles
  short8 qf[2];
  const int ti0 = wid * 2;
#pragma unroll
  for (int t2 = 0; t2 < 2; ++t2) {
    int i = (ti0 + t2) * 16 + l15;
    size_t base = COL ? (((size_t)b * 128 + i) * 128 + r) * 32
                      : (((size_t)b * 128 + r) * 128 + i) * 32;
    qf[t2] = *(const short8*)&qF[base + lg * 8];
  }
  f32x4 lgt[2][8];
#pragma unroll
  for (int t2 = 0; t2 < 2; ++t2)
#pragma unroll
    for (int tj = 0; tj < 8; ++tj)
#pragma unroll
      for (int e = 0; e < 4; ++e) lgt[t2][tj][e] = 0.f;
#pragma unroll
  for (int tj = 0; tj < 8; ++tj) {
    int j = tj * 16 + l15;
    size_t base = COL ? (((size_t)b * 128 + j) * 128 + r) * 32
                      : (((size_t)b * 128 + r) * 128 + j) * 32;
    short8 kf = *(const short8*)&kF[base + lg * 8];
#pragma unroll
    for (int t2 = 0; t2 < 2; ++t2)
      lgt[t2][tj] = __builtin_amdgcn_mfma_f32_16x16x32_bf16(kf, qf[t2], lgt[t2][tj], 0, 0, 0);
  }

  // ---- softmax over j (lane's j = tj*16 + lg*4 + rr at fixed i)
#pragma unroll
  for (int t2 = 0; t2 < 2; ++t2) {
    const int i = (ti0 + t2) * 16 + l15;
    if (COL) {
#pragma unroll
      for (int tj = 0; tj < 8; ++tj)
#pragma unroll
        for (int rr = 0; rr < 4; ++rr)
          if (tj * 16 + lg * 4 + rr == i) lgt[t2][tj][rr] += 1.0f;
    }
    float m = -1e30f;
#pragma unroll
    for (int tj = 0; tj < 8; ++tj)
#pragma unroll
      for (int rr = 0; rr < 4; ++rr) m = fmaxf(m, lgt[t2][tj][rr]);
    m = fmaxf(m, __shfl_xor(m, 16, 64));
    m = fmaxf(m, __shfl_xor(m, 32, 64));
    float s = 0.f;
#pragma unroll
    for (int tj = 0; tj < 8; ++tj)
#pragma unroll
      for (int rr = 0; rr < 4; ++rr) {
        float e = __expf(lgt[t2][tj][rr] - m);
        lgt[t2][tj][rr] = e;
        s += e;
      }
    s += __shfl_xor(s, 16, 64);
    s += __shfl_xor(s, 32, 64);
    if (lg == 0) rsum[i] = s;
#pragma unroll
    for (int tj = 0; tj < 8; ++tj) {
      int slot = ((tj * 2) + (lg >> 1)) ^ (i & 7);
      int elem = i * 128 + slot * 8 + (lg & 1) * 4;
      uint2 v;
      v.x = pack2(lgt[t2][tj][0], lgt[t2][tj][1]);
      v.y = pack2(lgt[t2][tj][2], lgt[t2][tj][3]);
      *(uint2*)&psm[elem] = v;
    }
  }
  __syncthreads();

  // ---- PV: D[c][i] = sum_j V[c][j] P[i][j]
  float rinv[8];
#pragma unroll
  for (int nt = 0; nt < 8; ++nt) rinv[nt] = 1.0f / rsum[nt * 16 + l15];

  const int cbase = wid * 64;
  unsigned short* ou = (unsigned short*)outP;
#pragma unroll
  for (int cp = 0; cp < 2; ++cp) {
    short8 vf[2][4];
#pragma unroll
    for (int u = 0; u < 2; ++u) {
      int c = cbase + (cp * 2 + u) * 16 + l15;
#pragma unroll
      for (int ks = 0; ks < 4; ++ks)
        vf[u][ks] = *(const short8*)&vsrc[(((size_t)b * 256 + c) * 128 + r) * 128 + ks * 32 + lg * 8];
    }
    f32x4 acc[2][8];
#pragma unroll
    for (int u = 0; u < 2; ++u)
#pragma unroll
      for (int nt = 0; nt < 8; ++nt)
#pragma unroll
        for (int e = 0; e < 4; ++e) acc[u][nt][e] = 0.f;
#pragma unroll
    for (int ks = 0; ks < 4; ++ks)
#pragma unroll
      for (int nt = 0; nt < 8; ++nt) {
        int i = nt * 16 + l15;
        short8 pf = *(const short8*)&psm[i * 128 + (((ks * 4) + lg) ^ (i & 7)) * 8];
#pragma unroll
        for (int u = 0; u < 2; ++u)
          acc[u][nt] = __builtin_amdgcn_mfma_f32_16x16x32_bf16(vf[u][ks], pf, acc[u][nt], 0, 0, 0);
      }
#pragma unroll
    for (int u = 0; u < 2; ++u) {
      int ct = cp * 2 + u;
      int cg = wid * 8 + ct * 2 + (lg >> 1);
#pragma unroll
      for (int nt = 0; nt < 8; ++nt) {
        int i = nt * 16 + l15;
        float sc = rinv[nt];
        uint2 v;
        v.x = pack2(acc[u][nt][0] * sc, acc[u][nt][1] * sc);
        v.y = pack2(acc[u][nt][2] * sc, acc[u][nt][3] * sc);
        size_t elem = ((((size_t)b * 32 + cg) * 128 + r) * 128 + i) * 8 + (lg & 1) * 4;
        *(uint2*)&ou[elem] = v;
      }
    }
  }
}

// ---- twP[b][cg][h][w][8] += thP[b][cg][w][h][8]  (uint4 = 8 bf16 payloads)
__global__ __launch_bounds__(256) void packed_merge2(const bf16* __restrict__ thP,
                                                     bf16* __restrict__ twP) {
  __shared__ uint4 ts[32][33];
  const int tid = threadIdx.x;
  const int blk = blockIdx.x;
  const int tI = blk & 15;
  const int cg = (blk >> 4) & 31;
  const int b = blk >> 9;
  const int h0 = (tI >> 2) * 32, w0 = (tI & 3) * 32;
  const uint4* tp = (const uint4*)thP;
  uint4* tw = (uint4*)twP;
#pragma unroll
  for (int rep = 0; rep < 4; ++rep) {
    int cell = rep * 256 + tid;
    int ww = cell >> 5, hh = cell & 31;
    ts[ww][hh] = tp[(((size_t)b * 32 + cg) * 128 + (w0 + ww)) * 128 + (h0 + hh)];
  }
  __syncthreads();
#pragma unroll
  for (int rep = 0; rep < 4; ++rep) {
    int cell = rep * 256 + tid;
    int hh = cell >> 5, ww = cell & 31;
    size_t o = (((size_t)b * 32 + cg) * 128 + (h0 + hh)) * 128 + (w0 + ww);
    tw[o] = add8bf16(tw[o], ts[ww][hh]);
  }
}

// ---- final MFMA GEMM: out = gamma*(Wv @ t + 2bv) + x, t from twP (c8-packed bf16)
__global__ __launch_bounds__(512) void final_mfma(
    const bf16* __restrict__ twP, const bf16* __restrict__ Wvb,
    const float* __restrict__ x, const float* __restrict__ bv,
    const float* __restrict__ gamma, float* __restrict__ out) {
  __shared__ short As[256][64];
  __shared__ short Bs[128][64];
  const int tid = threadIdx.x;
  const int b = blockIdx.x >> 7, h = blockIdx.x & 127;
  const int lane = tid & 63;
  const int wid = tid >> 6;
  const int wm = wid >> 1, wn = wid & 1;
  const int l15 = lane & 15, lg = lane >> 4;
  const unsigned short* twu = (const unsigned short*)twP;

  f32x4 acc[4][4];
#pragma unroll
  for (int m = 0; m < 4; ++m)
#pragma unroll
    for (int n = 0; n < 4; ++n)
#pragma unroll
      for (int e = 0; e < 4; ++e) acc[m][n][e] = 0.f;

  for (int k0 = 0; k0 < 256; k0 += 64) {
    __syncthreads();
#pragma unroll
    for (int p = 0; p < 4; ++p) {
      int idx = p * 512 + tid;
      int co = idx >> 3, cg = idx & 7;
      uint4 v = *(const uint4*)&Wvb[(size_t)co * 256 + k0 + cg * 8];
      *(uint4*)&As[co][(cg ^ (co & 7)) * 8] = v;
    }
#pragma unroll
    for (int p = 0; p < 2; ++p) {
      int idx = p * 512 + tid;
      int w = idx & 127, cgL = idx >> 7;
      size_t g16 = (((size_t)b * 32 + (k0 >> 3) + cgL) * 128 + h) * 128 + w;
      uint4 v = *(const uint4*)&twu[g16 * 8];
      *(uint4*)&Bs[w][(cgL ^ (w & 7)) * 8] = v;
    }
    __syncthreads();
    short8 a[4][2], bb[4][2];
#pragma unroll
    for (int m = 0; m < 4; ++m)
#pragma unroll
      for (int kk = 0; kk < 2; ++kk) {
        int co = wm * 64 + m * 16 + l15;
        int cg = kk * 4 + lg;
        a[m][kk] = *(const short8*)&As[co][(cg ^ (co & 7)) * 8];
      }
#pragma unroll
    for (int n = 0; n < 4; ++n)
#pragma unroll
      for (int kk = 0; kk < 2; ++kk) {
        int w = wn * 64 + n * 16 + l15;
        int cg = kk * 4 + lg;
        bb[n][kk] = *(const short8*)&Bs[w][(cg ^ (w & 7)) * 8];
      }
#pragma unroll
    for (int kk = 0; kk < 2; ++kk)
#pragma unroll
      for (int m = 0; m < 4; ++m)
#pragma unroll
        for (int n = 0; n < 4; ++n)
          acc[m][n] = __builtin_amdgcn_mfma_f32_16x16x32_bf16(a[m][kk], bb[n][kk], acc[m][n], 0, 0, 0);
  }

  const float g = gamma[0];
  float bvv[4][4];
#pragma unroll
  for (int m = 0; m < 4; ++m)
#pragma unroll
    for (int rr = 0; rr < 4; ++rr)
      bvv[m][rr] = 2.0f * bv[wm * 64 + m * 16 + lg * 4 + rr];
#pragma unroll
  for (int m = 0; m < 4; ++m)
#pragma unroll
    for (int n = 0; n < 4; ++n) {
      int w = wn * 64 + n * 16 + l15;
#pragma unroll
      for (int rr = 0; rr < 4; ++rr) {
        int co = wm * 64 + m * 16 + lg * 4 + rr;
        size_t o = (((size_t)b * 256 + co) * 128 + h) * 128 + w;
        out[o] = g * (acc[m][n][rr] + bvv[m][rr]) + x[o];
      }
    }
}

extern "C" void kernel_launch(void* const* d_in, const int* in_sizes, int n_in,
                              void* d_out, int out_size, void* d_ws, size_t ws_size,
                              hipStream_t stream) {
  const float* x     = (const float*)d_in[0];
  const float* Wq    = (const float*)d_in[1];
  const float* bq    = (const float*)d_in[2];
  const float* Wk    = (const float*)d_in[3];
  const float* bk    = (const float*)d_in[4];
  const float* Wv    = (const float*)d_in[5];
  const float* bv    = (const float*)d_in[6];
  const float* gamma = (const float*)d_in[7];
  float* out = (float*)d_out;

  const size_t QSZ = (size_t)BN * HN * WN * CQn;  // 4,194,304
  const size_t XSZ = (size_t)BN * CN * HN * WN;   // 33,554,432
  bf16* wsb = (bf16*)d_ws;

  const size_t need = (2 * QSZ + 3 * XSZ + 65536) * sizeof(bf16);  // ~218 MB (proven fits)
  if (ws_size < need) {
    hipMemsetAsync(d_out, 0x7f, (size_t)out_size * sizeof(float), stream);
    return;
  }

  bf16* qF  = wsb;                      // [b][h][w][32]
  bf16* kF  = wsb + QSZ;                // [b][h][w][32]
  bf16* xbf = wsb + 2 * QSZ;            // [b][c][h][w] bf16 copy of x; later reused as thP
  bf16* xT  = wsb + 2 * QSZ + XSZ;      // [b][c][w][h]
  bf16* twP = wsb + 2 * QSZ + 2 * XSZ;  // c8-packed t accumulator
  bf16* Wvb = wsb + 2 * QSZ + 3 * XSZ;  // Wv bf16
  bf16* thP = xbf;                      // alias: xbf dead after attn row

  proj_qk3<<<2 * BN * HN, 256, 0, stream>>>(x, Wq, bq, Wk, bk, qF, kF, xbf);
  wv_to_bf16<<<256, 256, 0, stream>>>(Wv, Wvb);
  transpose_bf16<bf16><<<BN * CN * 16, 256, 0, stream>>>(xbf, xT);
  // row attention -> t_w into twP
  attn_mfma<false><<<BN * HN, 256, 0, stream>>>(qF, kF, xbf, twP);
  // column attention -> t_h^T into thP (overwrites xbf, which is dead now)
  attn_mfma<true><<<BN * WN, 256, 0, stream>>>(qF, kF, xT, thP);
  // twP += t_h (transposed back into packed layout)
  packed_merge2<<<BN * 32 * 16, 256, 0, stream>>>(thP, twP);
  // out = gamma*(Wv@t + 2bv) + x via MFMA
  final_mfma<<<BN * HN, 512, 0, stream>>>(twP, Wvb, x, bv, gamma, out);
}